// Round 9
// baseline (179.878 us; speedup 1.0000x reference)
//
#include <hip/hip_runtime.h>

// B=16, Lk=2048, Lq=256, DIM=512, HEADS=8, d_k=64 — f32 I/O, bf16 MFMA internally.
// out = softmax((G@Wq+bq) heads @ L^T * scale) @ L, merge heads, @ Wo + bo
#define KSTR 72   // attn P-buffer row stride (shorts)

typedef __attribute__((ext_vector_type(8))) short short8;  // 8 bf16 (4 VGPRs)
typedef __attribute__((ext_vector_type(4))) float f32x4;

#define EXP2F(x) __builtin_amdgcn_exp2f(x)

__device__ __forceinline__ unsigned short f2bf(float f) {   // RNE f32->bf16
    union { float f; unsigned u; } v; v.f = f;
    unsigned r = v.u + 0x7fff + ((v.u >> 16) & 1);
    return (unsigned short)(r >> 16);
}
__device__ __forceinline__ unsigned pk2(float a, float b) {
    return (unsigned)f2bf(a) | ((unsigned)f2bf(b) << 16);
}

// ---- W[512,512] f32 -> WF frag-order bf16: chunk (kt,ng) of 512 shorts holds
// B-frag elems j = W[32kt+8quad+j][16ng+c] at offset lane*8.
__global__ __launch_bounds__(256) void conv_W(const float* __restrict__ Wq,
                                              const float* __restrict__ Wo,
                                              unsigned short* __restrict__ WqF,
                                              unsigned short* __restrict__ WoF) {
    const float* W = blockIdx.y ? Wo : Wq;
    unsigned short* WF = blockIdx.y ? WoF : WqF;
    int g = blockIdx.x * 256 + threadIdx.x;       // [0, 32768)
    int lane = g & 63, ntg = (g >> 6) & 31, kt = g >> 11;
    int c = lane & 15, quad = lane >> 4;
    const float* wp = W + (size_t)(32 * kt + 8 * quad) * 512 + 16 * ntg + c;
    float v[8];
    #pragma unroll
    for (int j = 0; j < 8; j++) v[j] = wp[(size_t)j * 512];
    uint4 u;
    u.x = pk2(v[0], v[1]); u.y = pk2(v[2], v[3]);
    u.z = pk2(v[4], v[5]); u.w = pk2(v[6], v[7]);
    *(uint4*)(WF + (size_t)g * 8) = u;
}

// ---- L[16,2048,512] f32 -> KF + VF frag tensors (bf16), per (b,h,t) 64x64 tile.
__global__ __launch_bounds__(256) void conv_L(const float* __restrict__ Lmat,
                                              unsigned short* __restrict__ KF,
                                              unsigned short* __restrict__ VF) {
    __shared__ unsigned short KFs[4096];
    __shared__ unsigned short VFs[4096];
    const int blk = blockIdx.x;            // ((b*8+h)*32+t)
    const int t = blk & 31, h = (blk >> 5) & 7, b = blk >> 8;
    const int tid = threadIdx.x;
    const int key = tid & 63, wv = tid >> 6;   // 16 d's per thread

    const float* src = Lmat + ((size_t)(b * 2048 + 64 * t + key)) * 512 + 64 * h + 16 * wv;
    float4 a0 = *(const float4*)src;
    float4 a1 = *(const float4*)(src + 4);
    float4 a2 = *(const float4*)(src + 8);
    float4 a3 = *(const float4*)(src + 12);
    float vals[16] = {a0.x, a0.y, a0.z, a0.w, a1.x, a1.y, a1.z, a1.w,
                      a2.x, a2.y, a2.z, a2.w, a3.x, a3.y, a3.z, a3.w};
    #pragma unroll
    for (int i = 0; i < 16; i++) {
        int d = 16 * wv + i;
        unsigned short bv = f2bf(vals[i]);
        KFs[((((key >> 4) * 2 + (d >> 5)) * 64) + ((d >> 3) & 3) * 16 + (key & 15)) * 8 + (d & 7)] = bv;
        VFs[((((d >> 4) * 2 + (key >> 5)) * 64) + ((key >> 3) & 3) * 16 + (d & 15)) * 8 + (key & 7)] = bv;
    }
    __syncthreads();
    size_t gbase = (size_t)blk * 4096 + tid * 16;
    *(uint4*)(KF + gbase)     = *(const uint4*)&KFs[tid * 16];
    *(uint4*)(KF + gbase + 8) = *(const uint4*)&KFs[tid * 16 + 8];
    *(uint4*)(VF + gbase)     = *(const uint4*)&VFs[tid * 16];
    *(uint4*)(VF + gbase + 8) = *(const uint4*)&VFs[tid * 16 + 8];
}

// ---- gemm v3: C[M,512] = (A@W + bias)*oscale. 64x64 tile, BK=64, 256 thr.
// B-frag chunk (8 KB) staged into LDS per block (4 waves SHARE -> B L2
// traffic /4), double-buffered, 1 barrier/step. A-frags register-direct
// (contiguous 16B per lane) with 1-step prefetch.
template<bool A_BF16, bool OUT_BF16>
__global__ __launch_bounds__(256) void gemm_v3(const void* __restrict__ Ap,
                                               const unsigned short* __restrict__ WF,
                                               const float* __restrict__ bias,
                                               void* __restrict__ Cp,
                                               float oscale) {
    __shared__ __align__(16) unsigned short Bs[2][4096];   // 8 KB per buf

    const int tid = threadIdx.x;
    const int wv = tid >> 6, lane = tid & 63;
    const int c = lane & 15, quad = lane >> 4;
    const int m0 = blockIdx.x * 64, n0 = blockIdx.y * 64;
    const int row = m0 + 16 * wv + c;
    const int half = tid >> 7;           // which kt of the BK=64 pair
    const int toff = (tid & 127) * 16;   // shorts within the 4 KB chunk

    f32x4 acc[4];
    #pragma unroll
    for (int nt = 0; nt < 4; nt++) acc[nt] = (f32x4){0.f, 0.f, 0.f, 0.f};

    short8 afc[2], afn[2];
    uint4 br0, br1;

    // A-frags for step s (k = 64s + 32kkl + 8quad .. +7)
    #define LOAD_A(s, dst)                                                          \
        {                                                                           \
            _Pragma("unroll")                                                       \
            for (int kkl = 0; kkl < 2; kkl++) {                                     \
                if (A_BF16) {                                                       \
                    dst[kkl] = *(const short8*)((const unsigned short*)Ap +         \
                        (size_t)row * 512 + 64 * (s) + 32 * kkl + 8 * quad);        \
                } else {                                                            \
                    const float* ap_ = (const float*)Ap +                           \
                        (size_t)row * 512 + 64 * (s) + 32 * kkl + 8 * quad;         \
                    float4 x0 = *(const float4*)ap_;                                \
                    float4 x1 = *(const float4*)(ap_ + 4);                          \
                    dst[kkl][0] = (short)f2bf(x0.x); dst[kkl][1] = (short)f2bf(x0.y);\
                    dst[kkl][2] = (short)f2bf(x0.z); dst[kkl][3] = (short)f2bf(x0.w);\
                    dst[kkl][4] = (short)f2bf(x1.x); dst[kkl][5] = (short)f2bf(x1.y);\
                    dst[kkl][6] = (short)f2bf(x1.z); dst[kkl][7] = (short)f2bf(x1.w);\
                }                                                                   \
            }                                                                       \
        }
    // B chunk for step s: kt = 2s+half, 4 KB at (kt*32 + n0/16)*512 shorts
    #define LOAD_B(s)                                                               \
        {                                                                           \
            const unsigned short* src_ = WF +                                       \
                ((size_t)((2 * (s) + half) * 32 + (n0 >> 4))) * 512 + toff;         \
            br0 = *(const uint4*)src_;                                              \
            br1 = *(const uint4*)(src_ + 8);                                        \
        }

    LOAD_A(0, afc);
    LOAD_B(0);
    *(uint4*)&Bs[0][(half << 11) + toff]     = br0;
    *(uint4*)&Bs[0][(half << 11) + toff + 8] = br1;
    __syncthreads();

    int p = 0;
    for (int s = 0; s < 8; s++) {
        if (s < 7) { LOAD_B(s + 1); LOAD_A(s + 1, afn); }
        #pragma unroll
        for (int kkl = 0; kkl < 2; kkl++)
            #pragma unroll
            for (int nt = 0; nt < 4; nt++) {
                short8 bf = *(const short8*)&Bs[p][(kkl << 11) + (nt << 9) + lane * 8];
                acc[nt] = __builtin_amdgcn_mfma_f32_16x16x32_bf16(afc[kkl], bf, acc[nt], 0, 0, 0);
            }
        if (s < 7) {
            *(uint4*)&Bs[p ^ 1][(half << 11) + toff]     = br0;
            *(uint4*)&Bs[p ^ 1][(half << 11) + toff + 8] = br1;
            afc[0] = afn[0]; afc[1] = afn[1];
        }
        __syncthreads();
        p ^= 1;
    }
    #undef LOAD_A
    #undef LOAD_B

    #pragma unroll
    for (int nt = 0; nt < 4; nt++) {
        float bv = bias[n0 + 16 * nt + c];
        #pragma unroll
        for (int r = 0; r < 4; r++) {
            float v = (acc[nt][r] + bv) * oscale;
            size_t idx = (size_t)(m0 + 16 * wv + 4 * quad + r) * 512 + n0 + 16 * nt + c;
            if (OUT_BF16) ((unsigned short*)Cp)[idx] = f2bf(v);
            else          ((float*)Cp)[idx] = v;
        }
    }
}

// ---- MFMA flash attention, LDS-shared K/V: the 16 KB frag tile is staged
// into LDS ONCE per block (verbatim bulk copy — frag order preserved),
// double-buffered, 1 barrier/tile; all 4 waves ds_read their frags (L2
// traffic /4 vs register-direct). XCD swizzle keeps (b,h) siblings on one
// XCD. No-max softmax (Q pre-scaled by scale*log2e); row sums via ones-MFMA.
__global__ __launch_bounds__(256) void attn_frag(const unsigned short* __restrict__ Q,
                                                 const unsigned short* __restrict__ KF,
                                                 const unsigned short* __restrict__ VF,
                                                 unsigned short* __restrict__ X) {
    __shared__ __align__(16) unsigned short Ks[2][4096];
    __shared__ __align__(16) unsigned short Vs[2][4096];
    __shared__ __align__(16) unsigned short Pw[4][16 * KSTR];

    // swizzle: h = blockIdx%8 -> 4 qt siblings of one (b,h) share an XCD
    const int raw = blockIdx.x;
    const int h  = raw & 7;
    const int qt = (raw >> 3) & 3;
    const int b  = raw >> 5;
    const int tid = threadIdx.x;
    const int wv = tid >> 6, lane = tid & 63;
    const int c = lane & 15, quad = lane >> 4;

    short8 qa[2];
    {
        const unsigned short* qsrc =
            Q + ((size_t)(b * 256 + qt * 64 + 16 * wv + c)) * 512 + h * 64;
        qa[0] = *(const short8*)(qsrc + 8 * quad);
        qa[1] = *(const short8*)(qsrc + 32 + 8 * quad);
    }
    short8 ones;
    #pragma unroll
    for (int i = 0; i < 8; i++) ones[i] = (short)0x3F80;   // bf16 1.0

    f32x4 oacc[4];
    #pragma unroll
    for (int dt = 0; dt < 4; dt++) oacc[dt] = (f32x4){0.f, 0.f, 0.f, 0.f};
    f32x4 lacc = (f32x4){0.f, 0.f, 0.f, 0.f};

    const int swc = (c >> 3) & 1;
    const int swr = (quad >> 1) & 1;

    const unsigned short* kfT = KF + ((size_t)((b * 8 + h) * 32)) * 4096 + tid * 16;
    const unsigned short* vfT = VF + ((size_t)((b * 8 + h) * 32)) * 4096 + tid * 16;

    // stage tile 0
    {
        uint4 k0 = *(const uint4*)kfT;
        uint4 k1 = *(const uint4*)(kfT + 8);
        uint4 v0 = *(const uint4*)vfT;
        uint4 v1 = *(const uint4*)(vfT + 8);
        *(uint4*)&Ks[0][tid * 16]     = k0;
        *(uint4*)&Ks[0][tid * 16 + 8] = k1;
        *(uint4*)&Vs[0][tid * 16]     = v0;
        *(uint4*)&Vs[0][tid * 16 + 8] = v1;
    }
    __syncthreads();

    int p = 0;
    for (int t = 0; t < 32; t++) {
        uint4 ka, kb2, va, vb2;
        if (t < 31) {   // prefetch next tile into registers (overlaps compute)
            const unsigned short* ksrc = kfT + (size_t)(t + 1) * 4096;
            const unsigned short* vsrc = vfT + (size_t)(t + 1) * 4096;
            ka  = *(const uint4*)ksrc;
            kb2 = *(const uint4*)(ksrc + 8);
            va  = *(const uint4*)vsrc;
            vb2 = *(const uint4*)(vsrc + 8);
        }

        // ---- S = Q @ K^T (exp2 domain) ----
        f32x4 sacc[4];
        #pragma unroll
        for (int nt = 0; nt < 4; nt++) sacc[nt] = (f32x4){0.f, 0.f, 0.f, 0.f};
        #pragma unroll
        for (int nt = 0; nt < 4; nt++)
            #pragma unroll
            for (int ksl = 0; ksl < 2; ksl++) {
                short8 kbf = *(const short8*)&Ks[p][((nt << 1) + ksl) * 512 + lane * 8];
                sacc[nt] = __builtin_amdgcn_mfma_f32_16x16x32_bf16(qa[ksl], kbf, sacc[nt], 0, 0, 0);
            }

        // ---- P = exp2(S) -> per-wave LDS round-trip to A-layout ----
        #pragma unroll
        for (int nt = 0; nt < 4; nt++)
            #pragma unroll
            for (int r = 0; r < 4; r++)
                Pw[wv][(4 * quad + r) * KSTR + ((16 * nt + c) ^ (8 * swr))] =
                    f2bf(EXP2F(sacc[nt][r]));
        short8 pa0 = *(const short8*)&Pw[wv][c * KSTR + (8 * (quad ^ swc))];
        short8 pa1 = *(const short8*)&Pw[wv][c * KSTR + 32 + (8 * (quad ^ swc))];

        // ---- O += P @ V ; row sums via ones-frag ----
        #pragma unroll
        for (int dt = 0; dt < 4; dt++) {
            short8 v0 = *(const short8*)&Vs[p][((dt << 1) + 0) * 512 + lane * 8];
            oacc[dt] = __builtin_amdgcn_mfma_f32_16x16x32_bf16(pa0, v0, oacc[dt], 0, 0, 0);
            short8 v1 = *(const short8*)&Vs[p][((dt << 1) + 1) * 512 + lane * 8];
            oacc[dt] = __builtin_amdgcn_mfma_f32_16x16x32_bf16(pa1, v1, oacc[dt], 0, 0, 0);
        }
        lacc = __builtin_amdgcn_mfma_f32_16x16x32_bf16(pa0, ones, lacc, 0, 0, 0);
        lacc = __builtin_amdgcn_mfma_f32_16x16x32_bf16(pa1, ones, lacc, 0, 0, 0);

        // ---- write prefetched tile to the other buffer ----
        if (t < 31) {
            *(uint4*)&Ks[p ^ 1][tid * 16]     = ka;
            *(uint4*)&Ks[p ^ 1][tid * 16 + 8] = kb2;
            *(uint4*)&Vs[p ^ 1][tid * 16]     = va;
            *(uint4*)&Vs[p ^ 1][tid * 16 + 8] = vb2;
        }
        __syncthreads();
        p ^= 1;
    }

    #pragma unroll
    for (int r = 0; r < 4; r++) {
        float inv = 1.f / lacc[r];
        size_t row = (size_t)(b * 256 + qt * 64 + 16 * wv + 4 * quad + r);
        unsigned short* xp = X + row * 512 + h * 64;
        #pragma unroll
        for (int dt = 0; dt < 4; dt++)
            xp[16 * dt + c] = f2bf(oacc[dt][r] * inv);
    }
}

// ---------------------------------------------------------------------------
extern "C" void kernel_launch(void* const* d_in, const int* in_sizes, int n_in,
                              void* d_out, int out_size, void* d_ws, size_t ws_size,
                              hipStream_t stream) {
    const float* Lmat = (const float*)d_in[0];  // [16,2048,512]
    const float* G    = (const float*)d_in[1];  // [16,256,512]
    const float* Wq   = (const float*)d_in[2];  // [512,512]
    const float* bq   = (const float*)d_in[3];  // [512]
    const float* Wo   = (const float*)d_in[4];  // [512,512]
    const float* bo   = (const float*)d_in[5];  // [512]
    float* out = (float*)d_out;                 // [16,256,512] f32

    const float SCe = 0.005524271728019903f * 1.4426950408889634f;  // scale*log2e
    dim3 gg(64, 8);

    // ws layout (bf16 elems): Qws 2M | Xws 2M | WqF 256K | WoF 256K | KF 16M | VF 16M
    unsigned short* Qws = (unsigned short*)d_ws;
    unsigned short* Xws = Qws + (size_t)2097152;
    unsigned short* WqF = Xws + (size_t)2097152;
    unsigned short* WoF = WqF + (size_t)262144;
    unsigned short* KF  = WoF + (size_t)262144;
    unsigned short* VF  = KF  + (size_t)16777216;

    conv_W<<<dim3(128, 2), 256, 0, stream>>>(Wq, Wo, WqF, WoF);
    conv_L<<<4096, 256, 0, stream>>>(Lmat, KF, VF);
    gemm_v3<false, true><<<gg, 256, 0, stream>>>(G, WqF, bq, Qws, SCe);
    attn_frag<<<512, 256, 0, stream>>>(Qws, KF, VF, Xws);
    gemm_v3<true, false><<<gg, 256, 0, stream>>>(Xws, WoF, bo, out, 1.0f);
}